// Round 1
// baseline (241.617 us; speedup 1.0000x reference)
//
#include <hip/hip_runtime.h>
#include <math.h>

#define BN 2
#define CC 256
#define NN 2304   // 48*48
#define KK 12

// ---------------- workspace layout (element offsets, all 4-byte) ----------------
// cls_g : BN*NN ints        @ 0
// cls_r : BN*NN ints        @ 4608
// cnt_g : BN*KK ints        @ 9216   (padded to 32)
// cnt_r : BN*KK ints        @ 9248   (padded to 32)
// idx_r : BN*KK*NN ints     @ 9280
// mean_g: BN*KK*CC floats   @ 64576
// mean_r: BN*KK*CC floats   @ 70720
// ug    : BN*NN*CC floats   @ 76864   (transposed unit gray features)
// ur    : BN*NN*CC floats   @ 1256512 (transposed unit rgb features)
#define OFF_CLS_G 0
#define OFF_CLS_R 4608
#define OFF_CNT_G 9216
#define OFF_CNT_R 9248
#define OFF_IDX_R 9280
#define OFF_MEAN_G 64576
#define OFF_MEAN_R 70720
#define OFF_UG 76864
#define OFF_UR 1256512

__global__ void zero_kernel(int* cnt_g, int* cnt_r) {
    int t = threadIdx.x;
    if (t < BN * KK) { cnt_g[t] = 0; cnt_r[t] = 0; }
}

// per-pixel class ids, per-class counts, compacted rgb pixel lists
__global__ void cls_kernel(const float* __restrict__ gl, const float* __restrict__ rl,
                           int* cls_g, int* cls_r, int* cnt_g, int* cnt_r, int* idx_r) {
    int t = blockIdx.x * blockDim.x + threadIdx.x;
    if (t >= BN * NN) return;
    int b = t / NN, i = t % NN;
    int kg = 0, kr = 0;
    for (int k = 0; k < KK; ++k) {
        if (gl[(b * KK + k) * NN + i] > 0.5f) kg = k;
        if (rl[(b * KK + k) * NN + i] > 0.5f) kr = k;
    }
    cls_g[t] = kg;
    cls_r[t] = kr;
    atomicAdd(&cnt_g[b * KK + kg], 1);
    int pos = atomicAdd(&cnt_r[b * KK + kr], 1);
    idx_r[(b * KK + kr) * NN + pos] = i;
}

// masked per-class per-channel means. grid = 2*BN*CC blocks, 256 threads.
__global__ void mean_kernel(const float* __restrict__ gf, const float* __restrict__ rf,
                            const int* __restrict__ cls_g, const int* __restrict__ cls_r,
                            const int* __restrict__ cnt_g, const int* __restrict__ cnt_r,
                            float* mean_g, float* mean_r) {
    int blk = blockIdx.x;
    int type = blk / (BN * CC);
    int rem = blk % (BN * CC);
    int b = rem / CC, c = rem % CC;
    const float* f = type ? rf : gf;
    const int* cls = type ? cls_r : cls_g;
    const int* cnt = type ? cnt_r : cnt_g;
    float* mean = type ? mean_r : mean_g;

    __shared__ float bins[256 * KK];
    int t = threadIdx.x;
    for (int k = 0; k < KK; ++k) bins[t * KK + k] = 0.f;
    for (int i = t; i < NN; i += 256) {
        int k = cls[b * NN + i];
        bins[t * KK + k] += f[((size_t)b * CC + c) * NN + i];
    }
    __syncthreads();
    if (t < KK) {
        float s = 0.f;
        for (int u = 0; u < 256; ++u) s += bins[u * KK + t];
        float cn = (float)cnt[b * KK + t];
        mean[(b * KK + t) * CC + c] = s / fmaxf(cn, 1.f);
    }
}

// center + L2-normalize each pixel's channel vector; write TRANSPOSED [b][pix][c]
// grid = 2 * BN * (NN/256) blocks, 256 threads (one pixel per thread)
__global__ void unit_kernel(const float* __restrict__ gf, const float* __restrict__ rf,
                            const int* __restrict__ cls_g, const int* __restrict__ cls_r,
                            const float* __restrict__ mean_g, const float* __restrict__ mean_r,
                            float* ug, float* ur) {
    const int CH = NN / 256;  // 9
    int blk = blockIdx.x;
    int type = blk / (BN * CH);
    int rem = blk % (BN * CH);
    int b = rem / CH, chunk = rem % CH;
    const float* f = type ? rf : gf;
    const int* cls = type ? cls_r : cls_g;
    const float* mean = type ? mean_r : mean_g;
    float* u = type ? ur : ug;

    __shared__ float lmean[KK * 257];  // +1 pad breaks bank aliasing
    for (int x = threadIdx.x; x < KK * CC; x += 256) {
        int k = x / CC, c = x % CC;
        lmean[k * 257 + c] = mean[(b * KK + k) * CC + c];
    }
    __syncthreads();

    int i = chunk * 256 + threadIdx.x;
    int k = cls[b * NN + i];
    const float* fb = f + (size_t)b * CC * NN + i;
    float ss = 0.f;
    for (int c = 0; c < CC; ++c) {
        float v = fb[(size_t)c * NN] - lmean[k * 257 + c];
        ss += v * v;
    }
    float recip = (ss > 0.f) ? (1.0f / sqrtf(ss)) : 1.0f;
    float* ub = u + ((size_t)b * NN + i) * CC;
    for (int c = 0; c < CC; ++c) {
        float v = fb[(size_t)c * NN] - lmean[k * 257 + c];
        ub[c] = v * recip;
    }
}

__device__ inline float bred(float v, float* red, bool is_max, int t) {
    int lane = t & 63, w = t >> 6;
    if (is_max) {
        for (int o = 32; o; o >>= 1) v = fmaxf(v, __shfl_down(v, o, 64));
    } else {
        for (int o = 32; o; o >>= 1) v += __shfl_down(v, o, 64);
    }
    if (lane == 0) red[w] = v;
    __syncthreads();
    float r = is_max ? fmaxf(fmaxf(red[0], red[1]), fmaxf(red[2], red[3]))
                     : (red[0] + red[1] + red[2] + red[3]);
    __syncthreads();
    return r;
}

// one block per output pixel (b,i): correlation row, softmax, weighted image sum
__global__ void out_kernel(const float* __restrict__ img, const int* __restrict__ cls_g,
                           const int* __restrict__ cnt_g, const int* __restrict__ cnt_r,
                           const int* __restrict__ idx_r,
                           const float* __restrict__ ug, const float* __restrict__ ur,
                           float* out) {
    int b = blockIdx.x / NN;
    int i = blockIdx.x % NN;
    int t = threadIdx.x;
    int k = cls_g[b * NN + i];
    bool valid = (k > 0) && (cnt_g[b * KK + k] > 1) && (cnt_r[b * KK + k] > 1);
    if (!valid) {
        if (t < 3) out[((size_t)b * 3 + t) * NN + i] = -1.0f;
        return;
    }
    __shared__ float sU[CC];
    __shared__ float logits[NN];
    __shared__ float red[4];

    const float* ugb = ug + ((size_t)b * NN + i) * CC;
    sU[t] = ugb[t];
    int Mr = cnt_r[b * KK + k];
    const int* list = idx_r + (b * KK + k) * NN;
    __syncthreads();

    // correlation logits: one key pixel per thread (strided)
    const float4* s4 = (const float4*)sU;
    for (int m = t; m < Mr; m += 256) {
        int j = list[m];
        const float4* u4 = (const float4*)(ur + ((size_t)b * NN + j) * CC);
        float dot = 0.f;
        #pragma unroll 8
        for (int c = 0; c < CC / 4; ++c) {
            float4 a = s4[c];
            float4 v = u4[c];
            dot += a.x * v.x + a.y * v.y + a.z * v.z + a.w * v.w;
        }
        logits[m] = dot;
    }
    __syncthreads();

    // softmax over the key list
    float mx = -1e30f;
    for (int m = t; m < Mr; m += 256) mx = fmaxf(mx, logits[m]);
    mx = bred(mx, red, true, t);

    float s = 0.f;
    for (int m = t; m < Mr; m += 256) {
        float e = __expf(logits[m] - mx);
        logits[m] = e;
        s += e;
    }
    float stot = bred(s, red, false, t);

    // weighted image sum, 3 channels
    float p0 = 0.f, p1 = 0.f, p2 = 0.f;
    for (int m = t; m < Mr; m += 256) {
        float e = logits[m];
        int j = list[m];
        p0 += e * img[((size_t)b * 3 + 0) * NN + j];
        p1 += e * img[((size_t)b * 3 + 1) * NN + j];
        p2 += e * img[((size_t)b * 3 + 2) * NN + j];
    }
    float r0 = bred(p0, red, false, t);
    float r1 = bred(p1, red, false, t);
    float r2 = bred(p2, red, false, t);
    if (t == 0) {
        float inv = 1.0f / stot;
        out[((size_t)b * 3 + 0) * NN + i] = r0 * inv;
        out[((size_t)b * 3 + 1) * NN + i] = r1 * inv;
        out[((size_t)b * 3 + 2) * NN + i] = r2 * inv;
    }
}

extern "C" void kernel_launch(void* const* d_in, const int* in_sizes, int n_in,
                              void* d_out, int out_size, void* d_ws, size_t ws_size,
                              hipStream_t stream) {
    const float* gf  = (const float*)d_in[0];
    const float* rf  = (const float*)d_in[1];
    const float* img = (const float*)d_in[2];
    const float* gl  = (const float*)d_in[3];
    const float* rl  = (const float*)d_in[4];
    float* out = (float*)d_out;
    float* ws = (float*)d_ws;

    int*   cls_g  = (int*)(ws + OFF_CLS_G);
    int*   cls_r  = (int*)(ws + OFF_CLS_R);
    int*   cnt_g  = (int*)(ws + OFF_CNT_G);
    int*   cnt_r  = (int*)(ws + OFF_CNT_R);
    int*   idx_r  = (int*)(ws + OFF_IDX_R);
    float* mean_g = ws + OFF_MEAN_G;
    float* mean_r = ws + OFF_MEAN_R;
    float* ug     = ws + OFF_UG;
    float* ur     = ws + OFF_UR;

    zero_kernel<<<1, 64, 0, stream>>>(cnt_g, cnt_r);
    cls_kernel<<<(BN * NN + 255) / 256, 256, 0, stream>>>(gl, rl, cls_g, cls_r,
                                                          cnt_g, cnt_r, idx_r);
    mean_kernel<<<2 * BN * CC, 256, 0, stream>>>(gf, rf, cls_g, cls_r, cnt_g, cnt_r,
                                                 mean_g, mean_r);
    unit_kernel<<<2 * BN * (NN / 256), 256, 0, stream>>>(gf, rf, cls_g, cls_r,
                                                         mean_g, mean_r, ug, ur);
    out_kernel<<<BN * NN, 256, 0, stream>>>(img, cls_g, cnt_g, cnt_r, idx_r, ug, ur, out);
}